// Round 1
// baseline (894.841 us; speedup 1.0000x reference)
//
#include <hip/hip_runtime.h>
#include <math.h>
#include <stdint.h>

// NeuralMJP forward, MI355X/gfx950.
//  * sample == one-hot(argmax(logits)) in fwd -> decoder = 32x32 table.
//  * argmax(softmax(z)) == argmax(z) -> y never materialized.
//  * fp32 only (no fp32 MFMA; bf16 flips Gumbel argmaxes -> catastrophic).
//  * Weight-delivery ladder:
//      R1 all-SMEM scalar fmac: per-j lgkmcnt(0) drain -> 38% VALU, 670us.
//      R2 LDS 16x uniform b128/j: DS-pipe-bound, 818us.
//      R4 VMEM: L1 returns 1KiB/wave-load, 1530us.
//      R5 LDS quad-split + DPP-fmac: 558us (DPP fmac ~6cyc issue).
//      R6 scalar w1 + DPP w2: 509us; VALU-busy 111k cyc/wave, of which
//         ~50k is the DPP 4-extra-cycle tax (32 dpp * 384 j * 4).
//      R7 (this): BOTH phases via s_load weights + v_pk_fma_f32 (VOP3P,
//         2 exact fp32 FMAs/inst, SGPR src0 allowed). Phase-1 chains
//         (a0,a1),(a2,a3) packed into pk halves via interleaved pw1 rows
//         -> per-chain rounding order identical to np. Phase-2 pairs
//         (lg[2k],lg[2k+1]) with broadcast activation. No LDS, no DPP.
//         ~32 pk + ~8 misc VALU insts per j vs ~73 (incl 32 @6cyc) before.

constexpr int kB = 524288;  // batch
constexpr int kD = 32;      // input dim
constexpr int kH = 128;     // hidden
constexpr int kS = 32;      // states

typedef __attribute__((ext_vector_type(2))) float f32x2;

// d_ws layout (bytes):
//   pw1   @ 0     : 3*128*32 f32 = 49152   row j of pass p, pk-interleaved:
//                   [w1[0],w1[8],w1[1],w1[9],..,w1[7],w1[15],
//                    w1[16],w1[24],..,w1[23],w1[31]]  (w1[i] = w1_p[i][j])
//   pb1   @ 49152 : 3*128   f32 = 1536
//   table @ 50688 : 32*32   f32 = 4096

// -------- prep: pack w1 (transposed, pk-interleaved) + b1 + decoder table --
__global__ __launch_bounds__(1024) void prep_kernel(
    const float* __restrict__ q_w1,  const float* __restrict__ q_b1,
    const float* __restrict__ gi_w1, const float* __restrict__ gi_b1,
    const float* __restrict__ go_w1, const float* __restrict__ go_b1,
    const float* __restrict__ dec_w1, const float* __restrict__ dec_b1,
    const float* __restrict__ dec_w2, const float* __restrict__ dec_b2,
    float* __restrict__ pw1, float* __restrict__ pb1, float* __restrict__ table)
{
    const int t = threadIdx.x;
    // decoder table: row k = relu(dec_w1[k,:] + dec_b1) @ dec_w2 + dec_b2
    {
        const int k = t >> 5, d = t & 31;
        float acc = 0.0f;
        #pragma unroll 4
        for (int j = 0; j < kH; ++j) {
            float a = dec_w1[k * kH + j] + dec_b1[j];
            a = fmaxf(a, 0.0f);
            acc = fmaf(a, dec_w2[j * kS + d], acc);
        }
        table[k * kS + d] = acc + dec_b2[d];
    }
    // w1 transposed + pk-pair-interleaved pack, plus compact b1 slab
    if (t < 3 * kH) {
        const int p = t >> 7;
        const int j = t & (kH - 1);
        const float* w1 = (p == 0) ? q_w1 : (p == 1) ? gi_w1 : go_w1;
        const float* b1 = (p == 0) ? q_b1 : (p == 1) ? gi_b1 : go_b1;
        float* row = pw1 + (size_t)(p * kH + j) * 32;
        #pragma unroll
        for (int i = 0; i < 8; ++i) {
            row[2 * i]          = w1[(i)      * kH + j];   // chain a0 elem i
            row[2 * i + 1]      = w1[(i + 8)  * kH + j];   // chain a1 elem i
            row[16 + 2 * i]     = w1[(i + 16) * kH + j];   // chain a2 elem i
            row[16 + 2 * i + 1] = w1[(i + 24) * kH + j];   // chain a3 elem i
        }
        pb1[t] = b1[j];
    }
}

// -------- main ------------------------------------------------------------
// v_pk_fma_f32: dst.lo = src0.lo*src1.lo + src2.lo ; same for .hi.
// Each half is an exact fmaf. src0 ("s") is the wave-uniform weight pair
// (one SGPR operand allowed on the constant bus); src1/src2 are VGPR pairs.
__device__ __forceinline__ void pk_fma(f32x2& acc, const f32x2 w, const f32x2 x)
{
    asm("v_pk_fma_f32 %0, %1, %2, %0" : "+v"(acc) : "s"(w), "v"(x));
}

__device__ __forceinline__ void mlp_pass(const f32x2* __restrict__ hA,  // (hv[i],   hv[i+8])
                                         const f32x2* __restrict__ hB,  // (hv[i+16], hv[i+24])
                                         const float* __restrict__ w1b, // interleaved rows, uniform
                                         const float* __restrict__ w2b, // natural rows, uniform
                                         const float* __restrict__ b1u, // uniform
                                         const float* __restrict__ b2,  // uniform
                                         float* __restrict__ lg)
{
    f32x2 L[16];
    #pragma unroll
    for (int k = 0; k < 16; ++k) L[k] = (f32x2)0.0f;
    // No unroll: one j's weights = 64 SGPRs live (+bases) fits the 102
    // budget; unroll 2 would want 128 -> SGPR spills. The per-j lgkmcnt(0)
    // drain (~K$/L2 latency) is hidden by multi-wave occupancy (no LDS now).
    for (int j = 0; j < kH; ++j) {
        const f32x2* __restrict__ w1r = reinterpret_cast<const f32x2*>(w1b + j * 32);
        const f32x2* __restrict__ w2r = reinterpret_cast<const f32x2*>(w2b + j * 32);
        const float bias = b1u[j];                       // uniform -> s_load
        // phase 1: 4 chains in 2 pk accumulators; per-chain order == R1..R6
        f32x2 p01 = (f32x2)0.0f, p23 = (f32x2)0.0f;
        #pragma unroll
        for (int i = 0; i < 8; ++i) {
            pk_fma(p01, w1r[i],     hA[i]);              // lo: a0, hi: a1
            pk_fma(p23, w1r[8 + i], hB[i]);              // lo: a2, hi: a3
        }
        float a = ((p01.x + p01.y) + (p23.x + p23.y)) + bias;  // dot, then bias
        a = fmaxf(a, 0.0f);
        // phase 2: rank-1 update, s ascending over j ascending (same order)
        f32x2 av; av.x = a; av.y = a;
        #pragma unroll
        for (int k = 0; k < 16; ++k) pk_fma(L[k], w2r[k], av);
    }
    #pragma unroll
    for (int k = 0; k < 16; ++k) {
        lg[2 * k]     = L[k].x + b2[2 * k];
        lg[2 * k + 1] = L[k].y + b2[2 * k + 1];
    }
}

__device__ __forceinline__ float tree_sum32(const float* __restrict__ v)
{
    float b0 = 0.f, b1 = 0.f, b2 = 0.f, b3 = 0.f;
    #pragma unroll
    for (int i = 0; i < 8; ++i) {
        b0 += v[i]; b1 += v[i + 8]; b2 += v[i + 16]; b3 += v[i + 24];
    }
    return (b0 + b1) + (b2 + b3);   // pairwise-ish, like np.sum
}

__device__ __forceinline__ void softmax32(const float* __restrict__ lg,
                                          float* __restrict__ p)
{
    float m = lg[0];
    #pragma unroll
    for (int s = 1; s < kS; ++s) m = fmaxf(m, lg[s]);
    float e[kS];
    #pragma unroll
    for (int s = 0; s < kS; ++s) e[s] = expf(lg[s] - m);
    const float Z = tree_sum32(e);
    #pragma unroll
    for (int s = 0; s < kS; ++s) p[s] = e[s] / Z;  // precise div, like np
}

__global__ __launch_bounds__(256, 3) void main_kernel(
    const float* __restrict__ h, const float* __restrict__ u,
    const float* __restrict__ qb2, const float* __restrict__ gib2,
    const float* __restrict__ gob2,
    const float* __restrict__ q_w2, const float* __restrict__ gi_w2,
    const float* __restrict__ go_w2,
    const float* __restrict__ pw1, const float* __restrict__ pb1,
    const float* __restrict__ table, float* __restrict__ out)
{
    const int tid = threadIdx.x;
    const int b = blockIdx.x * 256 + tid;

    // h into pk-pair layout matching the interleaved pw1 rows
    f32x2 hA[8], hB[8];
    {
        float hv[kD];
        const float4* h4 = reinterpret_cast<const float4*>(h + (size_t)b * kD);
        #pragma unroll
        for (int i = 0; i < 8; ++i) {
            float4 t = h4[i];
            hv[4 * i + 0] = t.x; hv[4 * i + 1] = t.y;
            hv[4 * i + 2] = t.z; hv[4 * i + 3] = t.w;
        }
        #pragma unroll
        for (int i = 0; i < 8; ++i) {
            hA[i].x = hv[i];      hA[i].y = hv[i + 8];
            hB[i].x = hv[i + 16]; hB[i].y = hv[i + 24];
        }
    }

    float lg[kS], q[kS], gi[kS];

    mlp_pass(hA, hB, pw1,               q_w2,  pb1,           qb2,  lg);
    softmax32(lg, q);
    mlp_pass(hA, hB, pw1 + kH * kD,     gi_w2, pb1 + kH,      gib2, lg);
    softmax32(lg, gi);
    mlp_pass(hA, hB, pw1 + 2 * kH * kD, go_w2, pb1 + 2 * kH,  gob2, lg);

    // g_out softmax fused with gumbel argmax (y never materialized)
    float m3 = lg[0];
    #pragma unroll
    for (int s = 1; s < kS; ++s) m3 = fmaxf(m3, lg[s]);
    float e3[kS];
    #pragma unroll
    for (int s = 0; s < kS; ++s) e3[s] = expf(lg[s] - m3);
    const float Z3 = tree_sum32(e3);
    const float qs = tree_sum32(q);   // == sum(q), computed like the reference

    float uv[kS];
    {
        const float4* u4 = reinterpret_cast<const float4*>(u + (size_t)b * kS);
        #pragma unroll
        for (int i = 0; i < 8; ++i) {
            float4 t = u4[i];
            uv[4 * i + 0] = t.x; uv[4 * i + 1] = t.y;
            uv[4 * i + 2] = t.z; uv[4 * i + 3] = t.w;
        }
    }

    float best = -__builtin_inff();
    int bi = 0;
    {
        #pragma clang fp contract(off)   // match np's per-op rounding here
        #pragma unroll
        for (int s = 0; s < kS; ++s) {
            const float gos = e3[s] / Z3;
            const float t1 = gi[s] * (qs - q[s]);
            const float t2 = gos * q[s];
            const float qn = q[s] + (t1 + t2);
            const float gn = -logf(-logf(uv[s] + 1e-20f) + 1e-20f);
            const float v  = logf(qn + 1e-12f) + gn;
            if (v > best) { best = v; bi = s; }   // strict >: first-index ties, like np.argmax
        }
    }

    // out[b,:] = table[bi,:]
    const float4* trow = reinterpret_cast<const float4*>(table + (size_t)bi * kS);
    float4* orow = reinterpret_cast<float4*>(out + (size_t)b * kD);
    #pragma unroll
    for (int i = 0; i < 8; ++i) orow[i] = trow[i];
}

extern "C" void kernel_launch(void* const* d_in, const int* in_sizes, int n_in,
                              void* d_out, int out_size, void* d_ws, size_t ws_size,
                              hipStream_t stream)
{
    const float* h      = (const float*)d_in[0];
    const float* u      = (const float*)d_in[1];
    const float* q_w1   = (const float*)d_in[2];
    const float* q_b1   = (const float*)d_in[3];
    const float* q_w2   = (const float*)d_in[4];
    const float* q_b2   = (const float*)d_in[5];
    const float* gi_w1  = (const float*)d_in[6];
    const float* gi_b1  = (const float*)d_in[7];
    const float* gi_w2  = (const float*)d_in[8];
    const float* gi_b2  = (const float*)d_in[9];
    const float* go_w1  = (const float*)d_in[10];
    const float* go_b1  = (const float*)d_in[11];
    const float* go_w2  = (const float*)d_in[12];
    const float* go_b2  = (const float*)d_in[13];
    const float* dec_w1 = (const float*)d_in[14];
    const float* dec_b1 = (const float*)d_in[15];
    const float* dec_w2 = (const float*)d_in[16];
    const float* dec_b2 = (const float*)d_in[17];

    float* pw1   = (float*)d_ws;                       // 49152 B
    float* pb1   = (float*)((char*)d_ws + 49152);      //  1536 B
    float* table = (float*)((char*)d_ws + 50688);      //  4096 B
    float* out   = (float*)d_out;

    prep_kernel<<<1, 1024, 0, stream>>>(q_w1, q_b1, gi_w1, gi_b1, go_w1, go_b1,
                                        dec_w1, dec_b1, dec_w2, dec_b2,
                                        pw1, pb1, table);
    main_kernel<<<kB / 256, 256, 0, stream>>>(h, u, q_b2, gi_b2, go_b2,
                                              q_w2, gi_w2, go_w2,
                                              pw1, pb1, table, out);
}

// Round 2
// 683.270 us; speedup vs baseline: 1.3096x; 1.3096x over previous
//
#include <hip/hip_runtime.h>
#include <math.h>
#include <stdint.h>

// NeuralMJP forward, MI355X/gfx950.
//  * sample == one-hot(argmax(logits)) in fwd -> decoder = 32x32 table.
//  * argmax(softmax(z)) == argmax(z) -> y never materialized.
//  * fp32 only (no fp32 MFMA; bf16 flips Gumbel argmaxes -> catastrophic).
//  * Weight-delivery ladder:
//      R1 all-SMEM scalar fmac: per-j lgkmcnt(0) drain -> 38% VALU, 670us.
//      R2 LDS 16x uniform b128/j: DS-pipe-bound, 818us.
//      R4 VMEM: L1 returns 1KiB/wave-load, 1530us.
//      R5 LDS quad-split + DPP-fmac: 558us (DPP fmac ~6cyc issue).
//      R6 scalar w1 + DPP w2: 509us; ~50k of 111k cyc/wave = DPP tax.
//      R7 both-phase SGPR + v_pk_fma_f32: 820us. pk_fma is ~6cyc (packed
//         fp32 is NOT 2x on gfx950) and 260B/j SMEM exposed K$ latency.
//      R8 (this): broadcast the ACTIVATION, not the weights. Quad lanes
//         cooperate: lane l keeps its quad-split W0/W1 (s-slice
//         {4l..4l+3, 16+4l..+3}) and accumulates that slice for all 4
//         quad elements; activations cross lanes via 3 v_mov_b32_dpp
//         rotations per j (vs 32 DPP fmacs in R6). All 64 phase-2 fmacs
//         are plain 2cyc VGPR fmacs. Per-pass epilogue: wave-synchronous
//         LDS quad-transpose (per-wave scratch, no barrier) restores
//         element order so the bit-exact softmax/sum/argmax chain is
//         unchanged. w2 slab (16KB) restaged per pass; stage loads issued
//         before transpose to hide latency. ~146 VALU cyc/j vs R6 ~289.

constexpr int kB = 524288;  // batch
constexpr int kD = 32;      // input dim
constexpr int kH = 128;     // hidden
constexpr int kS = 32;      // states

// d_ws layout (bytes):
//   pw1   @ 0     : 3*128*32 f32 = 49152   row j of pass p = w1_p[:,j]
//   pb1   @ 49152 : 3*128   f32 = 1536
//   table @ 50688 : 32*32   f32 = 4096

// -------- prep: pack w1 (transposed) + b1 + decoder table -----------------
__global__ __launch_bounds__(1024) void prep_kernel(
    const float* __restrict__ q_w1,  const float* __restrict__ q_b1,
    const float* __restrict__ gi_w1, const float* __restrict__ gi_b1,
    const float* __restrict__ go_w1, const float* __restrict__ go_b1,
    const float* __restrict__ dec_w1, const float* __restrict__ dec_b1,
    const float* __restrict__ dec_w2, const float* __restrict__ dec_b2,
    float* __restrict__ pw1, float* __restrict__ pb1, float* __restrict__ table)
{
    const int t = threadIdx.x;
    // decoder table: row k = relu(dec_w1[k,:] + dec_b1) @ dec_w2 + dec_b2
    {
        const int k = t >> 5, d = t & 31;
        float acc = 0.0f;
        #pragma unroll 4
        for (int j = 0; j < kH; ++j) {
            float a = dec_w1[k * kH + j] + dec_b1[j];
            a = fmaxf(a, 0.0f);
            acc = fmaf(a, dec_w2[j * kS + d], acc);
        }
        table[k * kS + d] = acc + dec_b2[d];
    }
    // w1 transposed pack: 3*128 rows of 32 floats + compact b1 slab
    if (t < 3 * kH) {
        const int p = t >> 7;
        const int j = t & (kH - 1);
        const float* w1 = (p == 0) ? q_w1 : (p == 1) ? gi_w1 : go_w1;
        const float* b1 = (p == 0) ? q_b1 : (p == 1) ? gi_b1 : go_b1;
        float* row = pw1 + (size_t)(p * kH + j) * 32;
        for (int i = 0; i < kD; ++i) row[i] = w1[i * kH + j];
        pb1[t] = b1[j];
    }
}

// -------- main ------------------------------------------------------------
// Per j: lane computes its OWN element's activation a (phase 1, SGPR w1),
// rotates a across the quad with 3 v_mov_b32_dpp, then accumulates its
// s-slice of the logits for all 4 quad elements with plain v_fmac.
// Bank r of L[] holds element (l+r)&3, s in {4l..4l+3, 16+4l..16+4l+3}.
__device__ __forceinline__ void mlp_pass(const float* __restrict__ hv,
                                         const float* __restrict__ w1b,  // uniform -> s_load
                                         const float* __restrict__ wq,   // LDS quad-split
                                         float b1lo, float b1hi,
                                         float* __restrict__ L)
{
    #pragma unroll
    for (int s = 0; s < kS; ++s) L[s] = 0.0f;
    #pragma unroll 2
    for (int j = 0; j < kH; ++j) {
        // phase-2 weights: quad-split LDS reads (same-address-per-quad
        // broadcast groups -> conflict-free), issued early.
        const float4 W0 = *reinterpret_cast<const float4*>(wq + j * kS);
        const float4 W1 = *reinterpret_cast<const float4*>(wq + j * kS + 16);
        // phase-1 weights: wave-uniform pointer -> s_load, scalar fmac srcs
        const float* __restrict__ w1r = w1b + j * kD;
        const float bsel = (j < 64) ? b1lo : b1hi;
        const float bias = __uint_as_float(
            (unsigned)__builtin_amdgcn_readlane((int)__float_as_uint(bsel), j & 63));
        // phase 1: 4 chains round-robin interleaved (per-chain order == R1..R7)
        float a0 = 0.f, a1c = 0.f, a2c = 0.f, a3c = 0.f;
        #pragma unroll
        for (int i = 0; i < 8; ++i) {
            a0  = fmaf(hv[i],      w1r[i],      a0);
            a1c = fmaf(hv[i + 8],  w1r[i + 8],  a1c);
            a2c = fmaf(hv[i + 16], w1r[i + 16], a2c);
            a3c = fmaf(hv[i + 24], w1r[i + 24], a3c);
        }
        float a = ((a0 + a1c) + (a2c + a3c)) + bias;  // dot, then bias (matches np)
        a = fmaxf(a, 0.0f);
        // quad rotation broadcast: A_r = activation of quad element (l+r)&3.
        // s_nop 1 covers the VALU-write -> DPP-read wait states on 'a'.
        float A1, A2, A3;
        asm("s_nop 1\n\t"
            "v_mov_b32_dpp %0, %3 quad_perm:[1,2,3,0] row_mask:0xf bank_mask:0xf\n\t"
            "v_mov_b32_dpp %1, %3 quad_perm:[2,3,0,1] row_mask:0xf bank_mask:0xf\n\t"
            "v_mov_b32_dpp %2, %3 quad_perm:[3,0,1,2] row_mask:0xf bank_mask:0xf"
            : "=&v"(A1), "=&v"(A2), "=&v"(A3)
            : "v"(a));
        // phase 2: 32 plain fmacs, j-ascending per (element,s) accumulator
        // (bit-identical accumulation order to R6's per-element chain).
        #define P2(k, w) \
            L[k]      = fmaf(a,  w, L[k]);      L[8 + k]  = fmaf(A1, w, L[8 + k]); \
            L[16 + k] = fmaf(A2, w, L[16 + k]); L[24 + k] = fmaf(A3, w, L[24 + k]);
        P2(0, W0.x) P2(1, W0.y) P2(2, W0.z) P2(3, W0.w)
        P2(4, W1.x) P2(5, W1.y) P2(6, W1.z) P2(7, W1.w)
        #undef P2
    }
}

// b2 added in slice layout (same value pattern for all 4 element banks);
// logits = acc + b2 exactly as before, before softmax.
__device__ __forceinline__ void add_b2_slice(float* __restrict__ L,
                                             const float4 B0, const float4 B1)
{
    #pragma unroll
    for (int r = 0; r < 4; ++r) {
        L[r*8+0] += B0.x; L[r*8+1] += B0.y; L[r*8+2] += B0.z; L[r*8+3] += B0.w;
        L[r*8+4] += B1.x; L[r*8+5] += B1.y; L[r*8+6] += B1.z; L[r*8+7] += B1.w;
    }
}

// Wave-synchronous quad transpose through per-wave LDS scratch (DS ops of
// one wave execute in order -> no barrier). Rows padded to 36 floats,
// quads to 148, chunk-XOR by quad -> ~4-8-way conflicts worst case.
__device__ __forceinline__ void quad_transpose(float* __restrict__ qb,
                                               int l, int xlow,
                                               const float* __restrict__ L,
                                               float* __restrict__ lg)
{
    const int swlo = (4 * l) ^ xlow;
    const int swhi = (16 + 4 * l) ^ xlow;
    #pragma unroll
    for (int r = 0; r < 4; ++r) {
        const int e = (l + r) & 3;
        *reinterpret_cast<float4*>(qb + e * 36 + swlo) =
            make_float4(L[r*8+0], L[r*8+1], L[r*8+2], L[r*8+3]);
        *reinterpret_cast<float4*>(qb + e * 36 + swhi) =
            make_float4(L[r*8+4], L[r*8+5], L[r*8+6], L[r*8+7]);
    }
    #pragma unroll
    for (int c = 0; c < 8; ++c) {
        const float4 v = *reinterpret_cast<const float4*>(qb + l * 36 + ((4 * c) ^ xlow));
        lg[4*c+0] = v.x; lg[4*c+1] = v.y; lg[4*c+2] = v.z; lg[4*c+3] = v.w;
    }
}

__device__ __forceinline__ float tree_sum32(const float* __restrict__ v)
{
    float b0 = 0.f, b1 = 0.f, b2 = 0.f, b3 = 0.f;
    #pragma unroll
    for (int i = 0; i < 8; ++i) {
        b0 += v[i]; b1 += v[i + 8]; b2 += v[i + 16]; b3 += v[i + 24];
    }
    return (b0 + b1) + (b2 + b3);   // pairwise-ish, like np.sum
}

__device__ __forceinline__ void softmax32(const float* __restrict__ lg,
                                          float* __restrict__ p)
{
    float m = lg[0];
    #pragma unroll
    for (int s = 1; s < kS; ++s) m = fmaxf(m, lg[s]);
    float e[kS];
    #pragma unroll
    for (int s = 0; s < kS; ++s) e[s] = expf(lg[s] - m);
    const float Z = tree_sum32(e);
    #pragma unroll
    for (int s = 0; s < kS; ++s) p[s] = e[s] / Z;  // precise div, like np
}

__global__ __launch_bounds__(256, 3) void main_kernel(
    const float* __restrict__ h, const float* __restrict__ u,
    const float* __restrict__ qb2, const float* __restrict__ gib2,
    const float* __restrict__ gob2,
    const float* __restrict__ q_w2, const float* __restrict__ gi_w2,
    const float* __restrict__ go_w2,
    const float* __restrict__ pw1, const float* __restrict__ pb1,
    const float* __restrict__ table, float* __restrict__ out)
{
    __shared__ float slab[kH * kS];     // 16KB: current pass w2 (restaged)
    __shared__ float scr[4 * 2368];     // 37888B: per-wave transpose scratch

    const int tid = threadIdx.x;
    const int lane = tid & 63;
    const int b = blockIdx.x * 256 + tid;
    const int l = tid & 3;              // quad pos == element slot
    const int qg = (tid >> 2) & 15;     // quad within wave
    float* const qb = scr + (tid >> 6) * 2368 + qg * 148;
    const int xlow = (qg & 7) << 2;
    const float* __restrict__ wq = slab + 4 * l;

    // stage pass-0 slab
    {
        float4* d4 = reinterpret_cast<float4*>(slab);
        const float4* s4 = reinterpret_cast<const float4*>(q_w2);
        #pragma unroll
        for (int k = 0; k < 4; ++k) d4[k * 256 + tid] = s4[k * 256 + tid];
    }

    float hv[kD];
    {
        const float4* h4 = reinterpret_cast<const float4*>(h + (size_t)b * kD);
        #pragma unroll
        for (int i = 0; i < 8; ++i) {
            float4 t = h4[i];
            hv[4 * i + 0] = t.x; hv[4 * i + 1] = t.y;
            hv[4 * i + 2] = t.z; hv[4 * i + 3] = t.w;
        }
    }
    __syncthreads();

    float L[kS], lg[kS], q[kS], gi[kS];

    // ---- pass 0 (q) ----
    {
        const float4 B0 = *reinterpret_cast<const float4*>(qb2 + 4 * l);
        const float4 B1 = *reinterpret_cast<const float4*>(qb2 + 16 + 4 * l);
        mlp_pass(hv, pw1, wq, pb1[lane], pb1[64 + lane], L);
        add_b2_slice(L, B0, B1);
    }
    __syncthreads();   // all waves done reading slab 0
    {
        // issue pass-1 slab loads; hide latency under transpose + softmax
        const float4* s4 = reinterpret_cast<const float4*>(gi_w2);
        float4 t0 = s4[tid], t1 = s4[256 + tid], t2 = s4[512 + tid], t3 = s4[768 + tid];
        quad_transpose(qb, l, xlow, L, lg);
        softmax32(lg, q);
        float4* d4 = reinterpret_cast<float4*>(slab);
        d4[tid] = t0; d4[256 + tid] = t1; d4[512 + tid] = t2; d4[768 + tid] = t3;
    }
    __syncthreads();   // slab 1 ready

    // ---- pass 1 (g_in) ----
    {
        const float4 B0 = *reinterpret_cast<const float4*>(gib2 + 4 * l);
        const float4 B1 = *reinterpret_cast<const float4*>(gib2 + 16 + 4 * l);
        mlp_pass(hv, pw1 + kH * kD, wq, pb1[128 + lane], pb1[192 + lane], L);
        add_b2_slice(L, B0, B1);
    }
    __syncthreads();   // all waves done reading slab 1
    {
        const float4* s4 = reinterpret_cast<const float4*>(go_w2);
        float4 t0 = s4[tid], t1 = s4[256 + tid], t2 = s4[512 + tid], t3 = s4[768 + tid];
        quad_transpose(qb, l, xlow, L, lg);
        softmax32(lg, gi);
        float4* d4 = reinterpret_cast<float4*>(slab);
        d4[tid] = t0; d4[256 + tid] = t1; d4[512 + tid] = t2; d4[768 + tid] = t3;
    }
    __syncthreads();   // slab 2 ready

    // ---- pass 2 (g_out) ----
    {
        const float4 B0 = *reinterpret_cast<const float4*>(gob2 + 4 * l);
        const float4 B1 = *reinterpret_cast<const float4*>(gob2 + 16 + 4 * l);
        mlp_pass(hv, pw1 + 2 * kH * kD, wq, pb1[256 + lane], pb1[320 + lane], L);
        add_b2_slice(L, B0, B1);
    }
    quad_transpose(qb, l, xlow, L, lg);

    // g_out softmax fused with gumbel argmax (y never materialized)
    float m3 = lg[0];
    #pragma unroll
    for (int s = 1; s < kS; ++s) m3 = fmaxf(m3, lg[s]);
    float e3[kS];
    #pragma unroll
    for (int s = 0; s < kS; ++s) e3[s] = expf(lg[s] - m3);
    const float Z3 = tree_sum32(e3);
    const float qs = tree_sum32(q);   // == sum(q), computed like the reference

    float uv[kS];
    {
        const float4* u4 = reinterpret_cast<const float4*>(u + (size_t)b * kS);
        #pragma unroll
        for (int i = 0; i < 8; ++i) {
            float4 t = u4[i];
            uv[4 * i + 0] = t.x; uv[4 * i + 1] = t.y;
            uv[4 * i + 2] = t.z; uv[4 * i + 3] = t.w;
        }
    }

    float best = -__builtin_inff();
    int bi = 0;
    {
        #pragma clang fp contract(off)   // match np's per-op rounding here
        #pragma unroll
        for (int s = 0; s < kS; ++s) {
            const float gos = e3[s] / Z3;
            const float t1 = gi[s] * (qs - q[s]);
            const float t2 = gos * q[s];
            const float qn = q[s] + (t1 + t2);
            const float gn = -logf(-logf(uv[s] + 1e-20f) + 1e-20f);
            const float v  = logf(qn + 1e-12f) + gn;
            if (v > best) { best = v; bi = s; }   // strict >: first-index ties, like np.argmax
        }
    }

    // out[b,:] = table[bi,:]
    const float4* trow = reinterpret_cast<const float4*>(table + (size_t)bi * kS);
    float4* orow = reinterpret_cast<float4*>(out + (size_t)b * kD);
    #pragma unroll
    for (int i = 0; i < 8; ++i) orow[i] = trow[i];
}

extern "C" void kernel_launch(void* const* d_in, const int* in_sizes, int n_in,
                              void* d_out, int out_size, void* d_ws, size_t ws_size,
                              hipStream_t stream)
{
    const float* h      = (const float*)d_in[0];
    const float* u      = (const float*)d_in[1];
    const float* q_w1   = (const float*)d_in[2];
    const float* q_b1   = (const float*)d_in[3];
    const float* q_w2   = (const float*)d_in[4];
    const float* q_b2   = (const float*)d_in[5];
    const float* gi_w1  = (const float*)d_in[6];
    const float* gi_b1  = (const float*)d_in[7];
    const float* gi_w2  = (const float*)d_in[8];
    const float* gi_b2  = (const float*)d_in[9];
    const float* go_w1  = (const float*)d_in[10];
    const float* go_b1  = (const float*)d_in[11];
    const float* go_w2  = (const float*)d_in[12];
    const float* go_b2  = (const float*)d_in[13];
    const float* dec_w1 = (const float*)d_in[14];
    const float* dec_b1 = (const float*)d_in[15];
    const float* dec_w2 = (const float*)d_in[16];
    const float* dec_b2 = (const float*)d_in[17];

    float* pw1   = (float*)d_ws;                       // 49152 B
    float* pb1   = (float*)((char*)d_ws + 49152);      //  1536 B
    float* table = (float*)((char*)d_ws + 50688);      //  4096 B
    float* out   = (float*)d_out;

    prep_kernel<<<1, 1024, 0, stream>>>(q_w1, q_b1, gi_w1, gi_b1, go_w1, go_b1,
                                        dec_w1, dec_b1, dec_w2, dec_b2,
                                        pw1, pb1, table);
    main_kernel<<<kB / 256, 256, 0, stream>>>(h, u, q_b2, gi_b2, go_b2,
                                              q_w2, gi_w2, go_w2,
                                              pw1, pb1, table, out);
}

// Round 3
// 573.949 us; speedup vs baseline: 1.5591x; 1.1905x over previous
//
#include <hip/hip_runtime.h>
#include <math.h>
#include <stdint.h>

// NeuralMJP forward, MI355X/gfx950.
//  * sample == one-hot(argmax(logits)) in fwd -> decoder = 32x32 table.
//  * argmax(softmax(z)) == argmax(z) -> y never materialized.
//  * fp32 only (no fp32 MFMA; bf16 flips Gumbel argmaxes -> catastrophic).
//  * Weight-delivery ladder:
//      R1 all-SMEM scalar fmac: per-j lgkmcnt(0) drain -> 38% VALU, 670us.
//      R2 LDS 16x uniform b128/j: DS-pipe-bound, 818us.
//      R4 VMEM: L1 returns 1KiB/wave-load, 1530us.
//      R5 LDS quad-split + DPP-fmac: 558us (DPP fmac ~6cyc issue).
//      R6 scalar w1 + DPP w2: 509us; ~50k of 111k cyc/wave = DPP tax.
//      R7 both-phase SGPR + v_pk_fma_f32: 820us (pk_fma ~6cyc, not 2x).
//      R8 quad-cooperative phase-2 (activation broadcast via 3 DPP movs,
//         all fmacs plain 2cyc): VALU/wave 111k->90k, BUT 54KB LDS
//         (16KB slab + 38KB transpose scratch) -> 2 blocks/CU -> 52%
//         VALUBusy, 578us. Latency-bound, not VALU-bound.
//      R9 (this): same compute core; transpose scratch OVERLAYED onto the
//         16KB slab (dead between passes). Each wave owns a 4KB quarter,
//         transposes in two 16-value rounds (same addresses reused;
//         wave-ordered DS => no intra-wave barrier), then slab restaged.
//         LDS 54272 -> 16384 => 5-6 blocks/CU. Cost: +2 barriers/epilogue.

constexpr int kB = 524288;  // batch
constexpr int kD = 32;      // input dim
constexpr int kH = 128;     // hidden
constexpr int kS = 32;      // states

// d_ws layout (bytes):
//   pw1   @ 0     : 3*128*32 f32 = 49152   row j of pass p = w1_p[:,j]
//   pb1   @ 49152 : 3*128   f32 = 1536
//   table @ 50688 : 32*32   f32 = 4096

// -------- prep: pack w1 (transposed) + b1 + decoder table -----------------
__global__ __launch_bounds__(1024) void prep_kernel(
    const float* __restrict__ q_w1,  const float* __restrict__ q_b1,
    const float* __restrict__ gi_w1, const float* __restrict__ gi_b1,
    const float* __restrict__ go_w1, const float* __restrict__ go_b1,
    const float* __restrict__ dec_w1, const float* __restrict__ dec_b1,
    const float* __restrict__ dec_w2, const float* __restrict__ dec_b2,
    float* __restrict__ pw1, float* __restrict__ pb1, float* __restrict__ table)
{
    const int t = threadIdx.x;
    // decoder table: row k = relu(dec_w1[k,:] + dec_b1) @ dec_w2 + dec_b2
    {
        const int k = t >> 5, d = t & 31;
        float acc = 0.0f;
        #pragma unroll 4
        for (int j = 0; j < kH; ++j) {
            float a = dec_w1[k * kH + j] + dec_b1[j];
            a = fmaxf(a, 0.0f);
            acc = fmaf(a, dec_w2[j * kS + d], acc);
        }
        table[k * kS + d] = acc + dec_b2[d];
    }
    // w1 transposed pack: 3*128 rows of 32 floats + compact b1 slab
    if (t < 3 * kH) {
        const int p = t >> 7;
        const int j = t & (kH - 1);
        const float* w1 = (p == 0) ? q_w1 : (p == 1) ? gi_w1 : go_w1;
        const float* b1 = (p == 0) ? q_b1 : (p == 1) ? gi_b1 : go_b1;
        float* row = pw1 + (size_t)(p * kH + j) * 32;
        for (int i = 0; i < kD; ++i) row[i] = w1[i * kH + j];
        pb1[t] = b1[j];
    }
}

// -------- main ------------------------------------------------------------
// Per j: lane computes its OWN element's activation a (phase 1, SGPR w1),
// rotates a across the quad with 3 v_mov_b32_dpp, then accumulates its
// s-slice of the logits for all 4 quad elements with plain v_fmac.
// Bank r of L[] holds element (l+r)&3, s in {4l..4l+3, 16+4l..16+4l+3}.
__device__ __forceinline__ void mlp_pass(const float* __restrict__ hv,
                                         const float* __restrict__ w1b,  // uniform -> s_load
                                         const float* __restrict__ wq,   // LDS quad-split
                                         float b1lo, float b1hi,
                                         float* __restrict__ L)
{
    #pragma unroll
    for (int s = 0; s < kS; ++s) L[s] = 0.0f;
    #pragma unroll 2
    for (int j = 0; j < kH; ++j) {
        // phase-2 weights: quad-split LDS reads (same-address-per-quad
        // broadcast groups -> conflict-free), issued early.
        const float4 W0 = *reinterpret_cast<const float4*>(wq + j * kS);
        const float4 W1 = *reinterpret_cast<const float4*>(wq + j * kS + 16);
        // phase-1 weights: wave-uniform pointer -> s_load, scalar fmac srcs
        const float* __restrict__ w1r = w1b + j * kD;
        const float bsel = (j < 64) ? b1lo : b1hi;
        const float bias = __uint_as_float(
            (unsigned)__builtin_amdgcn_readlane((int)__float_as_uint(bsel), j & 63));
        // phase 1: 4 chains round-robin interleaved (per-chain order == R1..R8)
        float a0 = 0.f, a1c = 0.f, a2c = 0.f, a3c = 0.f;
        #pragma unroll
        for (int i = 0; i < 8; ++i) {
            a0  = fmaf(hv[i],      w1r[i],      a0);
            a1c = fmaf(hv[i + 8],  w1r[i + 8],  a1c);
            a2c = fmaf(hv[i + 16], w1r[i + 16], a2c);
            a3c = fmaf(hv[i + 24], w1r[i + 24], a3c);
        }
        float a = ((a0 + a1c) + (a2c + a3c)) + bias;  // dot, then bias (matches np)
        a = fmaxf(a, 0.0f);
        // quad rotation broadcast: A_r = activation of quad element (l+r)&3.
        // s_nop 1 covers the VALU-write -> DPP-read wait states on 'a'.
        float A1, A2, A3;
        asm("s_nop 1\n\t"
            "v_mov_b32_dpp %0, %3 quad_perm:[1,2,3,0] row_mask:0xf bank_mask:0xf\n\t"
            "v_mov_b32_dpp %1, %3 quad_perm:[2,3,0,1] row_mask:0xf bank_mask:0xf\n\t"
            "v_mov_b32_dpp %2, %3 quad_perm:[3,0,1,2] row_mask:0xf bank_mask:0xf"
            : "=&v"(A1), "=&v"(A2), "=&v"(A3)
            : "v"(a));
        // phase 2: 32 plain fmacs, j-ascending per (element,s) accumulator
        // (bit-identical accumulation order to R6/R8 per-element chain).
        #define P2(k, w) \
            L[k]      = fmaf(a,  w, L[k]);      L[8 + k]  = fmaf(A1, w, L[8 + k]); \
            L[16 + k] = fmaf(A2, w, L[16 + k]); L[24 + k] = fmaf(A3, w, L[24 + k]);
        P2(0, W0.x) P2(1, W0.y) P2(2, W0.z) P2(3, W0.w)
        P2(4, W1.x) P2(5, W1.y) P2(6, W1.z) P2(7, W1.w)
        #undef P2
    }
}

// b2 added in slice layout (same value pattern for all 4 element banks);
// logits = acc + b2 exactly as before, before softmax.
__device__ __forceinline__ void add_b2_slice(float* __restrict__ L,
                                             const float4 B0, const float4 B1)
{
    #pragma unroll
    for (int r = 0; r < 4; ++r) {
        L[r*8+0] += B0.x; L[r*8+1] += B0.y; L[r*8+2] += B0.z; L[r*8+3] += B0.w;
        L[r*8+4] += B1.x; L[r*8+5] += B1.y; L[r*8+6] += B1.z; L[r*8+7] += B1.w;
    }
}

// One 16-value round of the wave-synchronous quad transpose through the
// wave's private 4KB quarter of the (dead) slab. DS ops of one wave execute
// in order -> no barrier between write and read, and round 1 may reuse the
// same addresses as round 0. xq = 4*(qg&3) XOR-slot swizzle spreads the
// chunk slots across banks (conflicts measured negligible in R8).
// Round R: L bank r, regs [r*8+R*4 .. +3] = element (l+r)&3, s = R*16+4l+k.
__device__ __forceinline__ void quad_transpose16(float* __restrict__ qb,
                                                 int l, int xq, int R,
                                                 const float* __restrict__ L,
                                                 float* __restrict__ lg)
{
    #pragma unroll
    for (int r = 0; r < 4; ++r) {
        const int e = (l + r) & 3;
        *reinterpret_cast<float4*>(qb + e * 16 + ((4 * l) ^ xq)) =
            make_float4(L[r*8 + R*4 + 0], L[r*8 + R*4 + 1],
                        L[r*8 + R*4 + 2], L[r*8 + R*4 + 3]);
    }
    #pragma unroll
    for (int c = 0; c < 4; ++c) {
        const float4 v = *reinterpret_cast<const float4*>(qb + l * 16 + ((4 * c) ^ xq));
        lg[R*16 + 4*c + 0] = v.x; lg[R*16 + 4*c + 1] = v.y;
        lg[R*16 + 4*c + 2] = v.z; lg[R*16 + 4*c + 3] = v.w;
    }
}

__device__ __forceinline__ float tree_sum32(const float* __restrict__ v)
{
    float b0 = 0.f, b1 = 0.f, b2 = 0.f, b3 = 0.f;
    #pragma unroll
    for (int i = 0; i < 8; ++i) {
        b0 += v[i]; b1 += v[i + 8]; b2 += v[i + 16]; b3 += v[i + 24];
    }
    return (b0 + b1) + (b2 + b3);   // pairwise-ish, like np.sum
}

__device__ __forceinline__ void softmax32(const float* __restrict__ lg,
                                          float* __restrict__ p)
{
    float m = lg[0];
    #pragma unroll
    for (int s = 1; s < kS; ++s) m = fmaxf(m, lg[s]);
    float e[kS];
    #pragma unroll
    for (int s = 0; s < kS; ++s) e[s] = expf(lg[s] - m);
    const float Z = tree_sum32(e);
    #pragma unroll
    for (int s = 0; s < kS; ++s) p[s] = e[s] / Z;  // precise div, like np
}

__global__ __launch_bounds__(256, 4) void main_kernel(
    const float* __restrict__ h, const float* __restrict__ u,
    const float* __restrict__ qb2, const float* __restrict__ gib2,
    const float* __restrict__ gob2,
    const float* __restrict__ q_w2, const float* __restrict__ gi_w2,
    const float* __restrict__ go_w2,
    const float* __restrict__ pw1, const float* __restrict__ pb1,
    const float* __restrict__ table, float* __restrict__ out)
{
    __shared__ float slab[kH * kS];   // 16KB, triple duty: w2 slab of the
                                      // current pass / per-wave transpose
                                      // scratch between passes / restaged.

    const int tid = threadIdx.x;
    const int lane = tid & 63;
    const int b = blockIdx.x * 256 + tid;
    const int l = tid & 3;              // quad pos == element slot
    const int qg = (tid >> 2) & 15;     // quad within wave
    const int xq = (qg & 3) << 2;       // XOR slot swizzle
    float* const qb = slab + (tid >> 6) * 1024 + qg * 64;  // wave quarter
    const float* __restrict__ wq = slab + 4 * l;

    // stage pass-0 slab
    {
        float4* d4 = reinterpret_cast<float4*>(slab);
        const float4* s4 = reinterpret_cast<const float4*>(q_w2);
        #pragma unroll
        for (int k = 0; k < 4; ++k) d4[k * 256 + tid] = s4[k * 256 + tid];
    }

    float hv[kD];
    {
        const float4* h4 = reinterpret_cast<const float4*>(h + (size_t)b * kD);
        #pragma unroll
        for (int i = 0; i < 8; ++i) {
            float4 t = h4[i];
            hv[4 * i + 0] = t.x; hv[4 * i + 1] = t.y;
            hv[4 * i + 2] = t.z; hv[4 * i + 3] = t.w;
        }
    }
    __syncthreads();

    float L[kS], lg[kS], q[kS], gi[kS];

    // ---- pass 0 (q) ----
    {
        const float4 B0 = *reinterpret_cast<const float4*>(qb2 + 4 * l);
        const float4 B1 = *reinterpret_cast<const float4*>(qb2 + 16 + 4 * l);
        mlp_pass(hv, pw1, wq, pb1[lane], pb1[64 + lane], L);
        add_b2_slice(L, B0, B1);
    }
    __syncthreads();   // all waves done reading slab 0 -> usable as scratch
    {
        // issue pass-1 slab loads; latency hides under transpose + softmax
        const float4* s4 = reinterpret_cast<const float4*>(gi_w2);
        float4 t0 = s4[tid], t1 = s4[256 + tid], t2 = s4[512 + tid], t3 = s4[768 + tid];
        quad_transpose16(qb, l, xq, 0, L, lg);
        quad_transpose16(qb, l, xq, 1, L, lg);
        softmax32(lg, q);
        __syncthreads();   // all scratch reads done -> slab writable
        float4* d4 = reinterpret_cast<float4*>(slab);
        d4[tid] = t0; d4[256 + tid] = t1; d4[512 + tid] = t2; d4[768 + tid] = t3;
    }
    __syncthreads();   // slab 1 ready

    // ---- pass 1 (g_in) ----
    {
        const float4 B0 = *reinterpret_cast<const float4*>(gib2 + 4 * l);
        const float4 B1 = *reinterpret_cast<const float4*>(gib2 + 16 + 4 * l);
        mlp_pass(hv, pw1 + kH * kD, wq, pb1[128 + lane], pb1[192 + lane], L);
        add_b2_slice(L, B0, B1);
    }
    __syncthreads();   // all waves done reading slab 1
    {
        const float4* s4 = reinterpret_cast<const float4*>(go_w2);
        float4 t0 = s4[tid], t1 = s4[256 + tid], t2 = s4[512 + tid], t3 = s4[768 + tid];
        quad_transpose16(qb, l, xq, 0, L, lg);
        quad_transpose16(qb, l, xq, 1, L, lg);
        softmax32(lg, gi);
        __syncthreads();
        float4* d4 = reinterpret_cast<float4*>(slab);
        d4[tid] = t0; d4[256 + tid] = t1; d4[512 + tid] = t2; d4[768 + tid] = t3;
    }
    __syncthreads();   // slab 2 ready

    // ---- pass 2 (g_out) ----
    {
        const float4 B0 = *reinterpret_cast<const float4*>(gob2 + 4 * l);
        const float4 B1 = *reinterpret_cast<const float4*>(gob2 + 16 + 4 * l);
        mlp_pass(hv, pw1 + 2 * kH * kD, wq, pb1[256 + lane], pb1[320 + lane], L);
        add_b2_slice(L, B0, B1);
    }
    __syncthreads();   // slab 2 dead -> scratch
    quad_transpose16(qb, l, xq, 0, L, lg);
    quad_transpose16(qb, l, xq, 1, L, lg);

    // g_out softmax fused with gumbel argmax (y never materialized)
    float m3 = lg[0];
    #pragma unroll
    for (int s = 1; s < kS; ++s) m3 = fmaxf(m3, lg[s]);
    float e3[kS];
    #pragma unroll
    for (int s = 0; s < kS; ++s) e3[s] = expf(lg[s] - m3);
    const float Z3 = tree_sum32(e3);
    const float qs = tree_sum32(q);   // == sum(q), computed like the reference

    float uv[kS];
    {
        const float4* u4 = reinterpret_cast<const float4*>(u + (size_t)b * kS);
        #pragma unroll
        for (int i = 0; i < 8; ++i) {
            float4 t = u4[i];
            uv[4 * i + 0] = t.x; uv[4 * i + 1] = t.y;
            uv[4 * i + 2] = t.z; uv[4 * i + 3] = t.w;
        }
    }

    float best = -__builtin_inff();
    int bi = 0;
    {
        #pragma clang fp contract(off)   // match np's per-op rounding here
        #pragma unroll
        for (int s = 0; s < kS; ++s) {
            const float gos = e3[s] / Z3;
            const float t1 = gi[s] * (qs - q[s]);
            const float t2 = gos * q[s];
            const float qn = q[s] + (t1 + t2);
            const float gn = -logf(-logf(uv[s] + 1e-20f) + 1e-20f);
            const float v  = logf(qn + 1e-12f) + gn;
            if (v > best) { best = v; bi = s; }   // strict >: first-index ties, like np.argmax
        }
    }

    // out[b,:] = table[bi,:]
    const float4* trow = reinterpret_cast<const float4*>(table + (size_t)bi * kS);
    float4* orow = reinterpret_cast<float4*>(out + (size_t)b * kD);
    #pragma unroll
    for (int i = 0; i < 8; ++i) orow[i] = trow[i];
}

extern "C" void kernel_launch(void* const* d_in, const int* in_sizes, int n_in,
                              void* d_out, int out_size, void* d_ws, size_t ws_size,
                              hipStream_t stream)
{
    const float* h      = (const float*)d_in[0];
    const float* u      = (const float*)d_in[1];
    const float* q_w1   = (const float*)d_in[2];
    const float* q_b1   = (const float*)d_in[3];
    const float* q_w2   = (const float*)d_in[4];
    const float* q_b2   = (const float*)d_in[5];
    const float* gi_w1  = (const float*)d_in[6];
    const float* gi_b1  = (const float*)d_in[7];
    const float* gi_w2  = (const float*)d_in[8];
    const float* gi_b2  = (const float*)d_in[9];
    const float* go_w1  = (const float*)d_in[10];
    const float* go_b1  = (const float*)d_in[11];
    const float* go_w2  = (const float*)d_in[12];
    const float* go_b2  = (const float*)d_in[13];
    const float* dec_w1 = (const float*)d_in[14];
    const float* dec_b1 = (const float*)d_in[15];
    const float* dec_w2 = (const float*)d_in[16];
    const float* dec_b2 = (const float*)d_in[17];

    float* pw1   = (float*)d_ws;                       // 49152 B
    float* pb1   = (float*)((char*)d_ws + 49152);      //  1536 B
    float* table = (float*)((char*)d_ws + 50688);      //  4096 B
    float* out   = (float*)d_out;

    prep_kernel<<<1, 1024, 0, stream>>>(q_w1, q_b1, gi_w1, gi_b1, go_w1, go_b1,
                                        dec_w1, dec_b1, dec_w2, dec_b2,
                                        pw1, pb1, table);
    main_kernel<<<kB / 256, 256, 0, stream>>>(h, u, q_b2, gi_b2, go_b2,
                                              q_w2, gi_w2, go_w2,
                                              pw1, pb1, table, out);
}

// Round 4
// 553.230 us; speedup vs baseline: 1.6175x; 1.0375x over previous
//
#include <hip/hip_runtime.h>
#include <math.h>
#include <stdint.h>

// NeuralMJP forward, MI355X/gfx950.
//  * sample == one-hot(argmax(logits)) in fwd -> decoder = 32x32 table.
//  * argmax(softmax(z)) == argmax(z) -> y never materialized.
//  * fp32 only (no fp32 MFMA; bf16 flips Gumbel argmaxes -> catastrophic).
//  * Weight-delivery ladder:
//      R1 all-SMEM scalar fmac: per-j lgkmcnt(0) drain -> 38% VALU, 670us.
//      R2 LDS 16x uniform b128/j: DS-pipe-bound, 818us.
//      R4 VMEM: L1 returns 1KiB/wave-load, 1530us.
//      R5 LDS quad-split + DPP-fmac: 558us (DPP fmac ~6cyc issue).
//      R6 scalar w1 + DPP w2: 509us; ~50k of 111k cyc/wave = DPP tax.
//      R7 both-phase SGPR + v_pk_fma_f32: 820us (pk_fma ~6cyc, not 2x).
//      R8 quad-cooperative phase-2 (activation broadcast via 3 DPP movs,
//         all fmacs plain 2cyc): VALU/wave 111k->90k, BUT 54KB LDS ->
//         2 blocks/CU -> 52% VALUBusy, 578us. Latency-bound.
//      R9 transpose scratch overlayed on the 16KB slab (LDS 54K->16K) but
//         launch_bounds(256,4) pushed VGPR 84->64: SPILLS. FETCH/WRITE
//         exploded to 222/293MB (spill traffic), 517us, VALUBusy 59%.
//      R10 (this): identical to R9 with launch_bounds(256,3) -> VGPR 84,
//         no spills (R8-proven), 16KB LDS kept. 4 blocks/CU (VGPR 84 is in
//         the <=128 bucket; LDS would allow 10). Expect spill traffic gone
//         and VALUBusy ~80%+ at ~50% occupancy; VALU floor ~307us.

constexpr int kB = 524288;  // batch
constexpr int kD = 32;      // input dim
constexpr int kH = 128;     // hidden
constexpr int kS = 32;      // states

// d_ws layout (bytes):
//   pw1   @ 0     : 3*128*32 f32 = 49152   row j of pass p = w1_p[:,j]
//   pb1   @ 49152 : 3*128   f32 = 1536
//   table @ 50688 : 32*32   f32 = 4096

// -------- prep: pack w1 (transposed) + b1 + decoder table -----------------
__global__ __launch_bounds__(1024) void prep_kernel(
    const float* __restrict__ q_w1,  const float* __restrict__ q_b1,
    const float* __restrict__ gi_w1, const float* __restrict__ gi_b1,
    const float* __restrict__ go_w1, const float* __restrict__ go_b1,
    const float* __restrict__ dec_w1, const float* __restrict__ dec_b1,
    const float* __restrict__ dec_w2, const float* __restrict__ dec_b2,
    float* __restrict__ pw1, float* __restrict__ pb1, float* __restrict__ table)
{
    const int t = threadIdx.x;
    // decoder table: row k = relu(dec_w1[k,:] + dec_b1) @ dec_w2 + dec_b2
    {
        const int k = t >> 5, d = t & 31;
        float acc = 0.0f;
        #pragma unroll 4
        for (int j = 0; j < kH; ++j) {
            float a = dec_w1[k * kH + j] + dec_b1[j];
            a = fmaxf(a, 0.0f);
            acc = fmaf(a, dec_w2[j * kS + d], acc);
        }
        table[k * kS + d] = acc + dec_b2[d];
    }
    // w1 transposed pack: 3*128 rows of 32 floats + compact b1 slab
    if (t < 3 * kH) {
        const int p = t >> 7;
        const int j = t & (kH - 1);
        const float* w1 = (p == 0) ? q_w1 : (p == 1) ? gi_w1 : go_w1;
        const float* b1 = (p == 0) ? q_b1 : (p == 1) ? gi_b1 : go_b1;
        float* row = pw1 + (size_t)(p * kH + j) * 32;
        for (int i = 0; i < kD; ++i) row[i] = w1[i * kH + j];
        pb1[t] = b1[j];
    }
}

// -------- main ------------------------------------------------------------
// Per j: lane computes its OWN element's activation a (phase 1, SGPR w1),
// rotates a across the quad with 3 v_mov_b32_dpp, then accumulates its
// s-slice of the logits for all 4 quad elements with plain v_fmac.
// Bank r of L[] holds element (l+r)&3, s in {4l..4l+3, 16+4l..16+4l+3}.
__device__ __forceinline__ void mlp_pass(const float* __restrict__ hv,
                                         const float* __restrict__ w1b,  // uniform -> s_load
                                         const float* __restrict__ wq,   // LDS quad-split
                                         float b1lo, float b1hi,
                                         float* __restrict__ L)
{
    #pragma unroll
    for (int s = 0; s < kS; ++s) L[s] = 0.0f;
    #pragma unroll 2
    for (int j = 0; j < kH; ++j) {
        // phase-2 weights: quad-split LDS reads (same-address-per-quad
        // broadcast groups -> conflict-free), issued early.
        const float4 W0 = *reinterpret_cast<const float4*>(wq + j * kS);
        const float4 W1 = *reinterpret_cast<const float4*>(wq + j * kS + 16);
        // phase-1 weights: wave-uniform pointer -> s_load, scalar fmac srcs
        const float* __restrict__ w1r = w1b + j * kD;
        const float bsel = (j < 64) ? b1lo : b1hi;
        const float bias = __uint_as_float(
            (unsigned)__builtin_amdgcn_readlane((int)__float_as_uint(bsel), j & 63));
        // phase 1: 4 chains round-robin interleaved (per-chain order == R1..R9)
        float a0 = 0.f, a1c = 0.f, a2c = 0.f, a3c = 0.f;
        #pragma unroll
        for (int i = 0; i < 8; ++i) {
            a0  = fmaf(hv[i],      w1r[i],      a0);
            a1c = fmaf(hv[i + 8],  w1r[i + 8],  a1c);
            a2c = fmaf(hv[i + 16], w1r[i + 16], a2c);
            a3c = fmaf(hv[i + 24], w1r[i + 24], a3c);
        }
        float a = ((a0 + a1c) + (a2c + a3c)) + bias;  // dot, then bias (matches np)
        a = fmaxf(a, 0.0f);
        // quad rotation broadcast: A_r = activation of quad element (l+r)&3.
        // s_nop 1 covers the VALU-write -> DPP-read wait states on 'a'.
        float A1, A2, A3;
        asm("s_nop 1\n\t"
            "v_mov_b32_dpp %0, %3 quad_perm:[1,2,3,0] row_mask:0xf bank_mask:0xf\n\t"
            "v_mov_b32_dpp %1, %3 quad_perm:[2,3,0,1] row_mask:0xf bank_mask:0xf\n\t"
            "v_mov_b32_dpp %2, %3 quad_perm:[3,0,1,2] row_mask:0xf bank_mask:0xf"
            : "=&v"(A1), "=&v"(A2), "=&v"(A3)
            : "v"(a));
        // phase 2: 32 plain fmacs, j-ascending per (element,s) accumulator
        // (bit-identical accumulation order to R6/R8 per-element chain).
        #define P2(k, w) \
            L[k]      = fmaf(a,  w, L[k]);      L[8 + k]  = fmaf(A1, w, L[8 + k]); \
            L[16 + k] = fmaf(A2, w, L[16 + k]); L[24 + k] = fmaf(A3, w, L[24 + k]);
        P2(0, W0.x) P2(1, W0.y) P2(2, W0.z) P2(3, W0.w)
        P2(4, W1.x) P2(5, W1.y) P2(6, W1.z) P2(7, W1.w)
        #undef P2
    }
}

// b2 added in slice layout (same value pattern for all 4 element banks);
// logits = acc + b2 exactly as before, before softmax.
__device__ __forceinline__ void add_b2_slice(float* __restrict__ L,
                                             const float4 B0, const float4 B1)
{
    #pragma unroll
    for (int r = 0; r < 4; ++r) {
        L[r*8+0] += B0.x; L[r*8+1] += B0.y; L[r*8+2] += B0.z; L[r*8+3] += B0.w;
        L[r*8+4] += B1.x; L[r*8+5] += B1.y; L[r*8+6] += B1.z; L[r*8+7] += B1.w;
    }
}

// One 16-value round of the wave-synchronous quad transpose through the
// wave's private 4KB quarter of the (dead) slab. DS ops of one wave execute
// in order -> no barrier between write and read, and round 1 may reuse the
// same addresses as round 0. xq = 4*(qg&3) XOR-slot swizzle spreads the
// chunk slots across banks (conflicts measured 0 in R9).
// Round R: L bank r, regs [r*8+R*4 .. +3] = element (l+r)&3, s = R*16+4l+k.
__device__ __forceinline__ void quad_transpose16(float* __restrict__ qb,
                                                 int l, int xq, int R,
                                                 const float* __restrict__ L,
                                                 float* __restrict__ lg)
{
    #pragma unroll
    for (int r = 0; r < 4; ++r) {
        const int e = (l + r) & 3;
        *reinterpret_cast<float4*>(qb + e * 16 + ((4 * l) ^ xq)) =
            make_float4(L[r*8 + R*4 + 0], L[r*8 + R*4 + 1],
                        L[r*8 + R*4 + 2], L[r*8 + R*4 + 3]);
    }
    #pragma unroll
    for (int c = 0; c < 4; ++c) {
        const float4 v = *reinterpret_cast<const float4*>(qb + l * 16 + ((4 * c) ^ xq));
        lg[R*16 + 4*c + 0] = v.x; lg[R*16 + 4*c + 1] = v.y;
        lg[R*16 + 4*c + 2] = v.z; lg[R*16 + 4*c + 3] = v.w;
    }
}

__device__ __forceinline__ float tree_sum32(const float* __restrict__ v)
{
    float b0 = 0.f, b1 = 0.f, b2 = 0.f, b3 = 0.f;
    #pragma unroll
    for (int i = 0; i < 8; ++i) {
        b0 += v[i]; b1 += v[i + 8]; b2 += v[i + 16]; b3 += v[i + 24];
    }
    return (b0 + b1) + (b2 + b3);   // pairwise-ish, like np.sum
}

__device__ __forceinline__ void softmax32(const float* __restrict__ lg,
                                          float* __restrict__ p)
{
    float m = lg[0];
    #pragma unroll
    for (int s = 1; s < kS; ++s) m = fmaxf(m, lg[s]);
    float e[kS];
    #pragma unroll
    for (int s = 0; s < kS; ++s) e[s] = expf(lg[s] - m);
    const float Z = tree_sum32(e);
    #pragma unroll
    for (int s = 0; s < kS; ++s) p[s] = e[s] / Z;  // precise div, like np
}

__global__ __launch_bounds__(256, 3) void main_kernel(
    const float* __restrict__ h, const float* __restrict__ u,
    const float* __restrict__ qb2, const float* __restrict__ gib2,
    const float* __restrict__ gob2,
    const float* __restrict__ q_w2, const float* __restrict__ gi_w2,
    const float* __restrict__ go_w2,
    const float* __restrict__ pw1, const float* __restrict__ pb1,
    const float* __restrict__ table, float* __restrict__ out)
{
    __shared__ float slab[kH * kS];   // 16KB, triple duty: w2 slab of the
                                      // current pass / per-wave transpose
                                      // scratch between passes / restaged.

    const int tid = threadIdx.x;
    const int lane = tid & 63;
    const int b = blockIdx.x * 256 + tid;
    const int l = tid & 3;              // quad pos == element slot
    const int qg = (tid >> 2) & 15;     // quad within wave
    const int xq = (qg & 3) << 2;       // XOR slot swizzle
    float* const qb = slab + (tid >> 6) * 1024 + qg * 64;  // wave quarter
    const float* __restrict__ wq = slab + 4 * l;

    // stage pass-0 slab
    {
        float4* d4 = reinterpret_cast<float4*>(slab);
        const float4* s4 = reinterpret_cast<const float4*>(q_w2);
        #pragma unroll
        for (int k = 0; k < 4; ++k) d4[k * 256 + tid] = s4[k * 256 + tid];
    }

    float hv[kD];
    {
        const float4* h4 = reinterpret_cast<const float4*>(h + (size_t)b * kD);
        #pragma unroll
        for (int i = 0; i < 8; ++i) {
            float4 t = h4[i];
            hv[4 * i + 0] = t.x; hv[4 * i + 1] = t.y;
            hv[4 * i + 2] = t.z; hv[4 * i + 3] = t.w;
        }
    }
    __syncthreads();

    float L[kS], lg[kS], q[kS], gi[kS];

    // ---- pass 0 (q) ----
    {
        const float4 B0 = *reinterpret_cast<const float4*>(qb2 + 4 * l);
        const float4 B1 = *reinterpret_cast<const float4*>(qb2 + 16 + 4 * l);
        mlp_pass(hv, pw1, wq, pb1[lane], pb1[64 + lane], L);
        add_b2_slice(L, B0, B1);
    }
    __syncthreads();   // all waves done reading slab 0 -> usable as scratch
    {
        // issue pass-1 slab loads; latency hides under transpose + softmax
        const float4* s4 = reinterpret_cast<const float4*>(gi_w2);
        float4 t0 = s4[tid], t1 = s4[256 + tid], t2 = s4[512 + tid], t3 = s4[768 + tid];
        quad_transpose16(qb, l, xq, 0, L, lg);
        quad_transpose16(qb, l, xq, 1, L, lg);
        softmax32(lg, q);
        __syncthreads();   // all scratch reads done -> slab writable
        float4* d4 = reinterpret_cast<float4*>(slab);
        d4[tid] = t0; d4[256 + tid] = t1; d4[512 + tid] = t2; d4[768 + tid] = t3;
    }
    __syncthreads();   // slab 1 ready

    // ---- pass 1 (g_in) ----
    {
        const float4 B0 = *reinterpret_cast<const float4*>(gib2 + 4 * l);
        const float4 B1 = *reinterpret_cast<const float4*>(gib2 + 16 + 4 * l);
        mlp_pass(hv, pw1 + kH * kD, wq, pb1[128 + lane], pb1[192 + lane], L);
        add_b2_slice(L, B0, B1);
    }
    __syncthreads();   // all waves done reading slab 1
    {
        const float4* s4 = reinterpret_cast<const float4*>(go_w2);
        float4 t0 = s4[tid], t1 = s4[256 + tid], t2 = s4[512 + tid], t3 = s4[768 + tid];
        quad_transpose16(qb, l, xq, 0, L, lg);
        quad_transpose16(qb, l, xq, 1, L, lg);
        softmax32(lg, gi);
        __syncthreads();
        float4* d4 = reinterpret_cast<float4*>(slab);
        d4[tid] = t0; d4[256 + tid] = t1; d4[512 + tid] = t2; d4[768 + tid] = t3;
    }
    __syncthreads();   // slab 2 ready

    // ---- pass 2 (g_out) ----
    {
        const float4 B0 = *reinterpret_cast<const float4*>(gob2 + 4 * l);
        const float4 B1 = *reinterpret_cast<const float4*>(gob2 + 16 + 4 * l);
        mlp_pass(hv, pw1 + 2 * kH * kD, wq, pb1[256 + lane], pb1[320 + lane], L);
        add_b2_slice(L, B0, B1);
    }
    __syncthreads();   // slab 2 dead -> scratch
    quad_transpose16(qb, l, xq, 0, L, lg);
    quad_transpose16(qb, l, xq, 1, L, lg);

    // g_out softmax fused with gumbel argmax (y never materialized)
    float m3 = lg[0];
    #pragma unroll
    for (int s = 1; s < kS; ++s) m3 = fmaxf(m3, lg[s]);
    float e3[kS];
    #pragma unroll
    for (int s = 0; s < kS; ++s) e3[s] = expf(lg[s] - m3);
    const float Z3 = tree_sum32(e3);
    const float qs = tree_sum32(q);   // == sum(q), computed like the reference

    float uv[kS];
    {
        const float4* u4 = reinterpret_cast<const float4*>(u + (size_t)b * kS);
        #pragma unroll
        for (int i = 0; i < 8; ++i) {
            float4 t = u4[i];
            uv[4 * i + 0] = t.x; uv[4 * i + 1] = t.y;
            uv[4 * i + 2] = t.z; uv[4 * i + 3] = t.w;
        }
    }

    float best = -__builtin_inff();
    int bi = 0;
    {
        #pragma clang fp contract(off)   // match np's per-op rounding here
        #pragma unroll
        for (int s = 0; s < kS; ++s) {
            const float gos = e3[s] / Z3;
            const float t1 = gi[s] * (qs - q[s]);
            const float t2 = gos * q[s];
            const float qn = q[s] + (t1 + t2);
            const float gn = -logf(-logf(uv[s] + 1e-20f) + 1e-20f);
            const float v  = logf(qn + 1e-12f) + gn;
            if (v > best) { best = v; bi = s; }   // strict >: first-index ties, like np.argmax
        }
    }

    // out[b,:] = table[bi,:]
    const float4* trow = reinterpret_cast<const float4*>(table + (size_t)bi * kS);
    float4* orow = reinterpret_cast<float4*>(out + (size_t)b * kD);
    #pragma unroll
    for (int i = 0; i < 8; ++i) orow[i] = trow[i];
}

extern "C" void kernel_launch(void* const* d_in, const int* in_sizes, int n_in,
                              void* d_out, int out_size, void* d_ws, size_t ws_size,
                              hipStream_t stream)
{
    const float* h      = (const float*)d_in[0];
    const float* u      = (const float*)d_in[1];
    const float* q_w1   = (const float*)d_in[2];
    const float* q_b1   = (const float*)d_in[3];
    const float* q_w2   = (const float*)d_in[4];
    const float* q_b2   = (const float*)d_in[5];
    const float* gi_w1  = (const float*)d_in[6];
    const float* gi_b1  = (const float*)d_in[7];
    const float* gi_w2  = (const float*)d_in[8];
    const float* gi_b2  = (const float*)d_in[9];
    const float* go_w1  = (const float*)d_in[10];
    const float* go_b1  = (const float*)d_in[11];
    const float* go_w2  = (const float*)d_in[12];
    const float* go_b2  = (const float*)d_in[13];
    const float* dec_w1 = (const float*)d_in[14];
    const float* dec_b1 = (const float*)d_in[15];
    const float* dec_w2 = (const float*)d_in[16];
    const float* dec_b2 = (const float*)d_in[17];

    float* pw1   = (float*)d_ws;                       // 49152 B
    float* pb1   = (float*)((char*)d_ws + 49152);      //  1536 B
    float* table = (float*)((char*)d_ws + 50688);      //  4096 B
    float* out   = (float*)d_out;

    prep_kernel<<<1, 1024, 0, stream>>>(q_w1, q_b1, gi_w1, gi_b1, go_w1, go_b1,
                                        dec_w1, dec_b1, dec_w2, dec_b2,
                                        pw1, pb1, table);
    main_kernel<<<kB / 256, 256, 0, stream>>>(h, u, q_b2, gi_b2, go_b2,
                                              q_w2, gi_w2, go_w2,
                                              pw1, pb1, table, out);
}